// Round 5
// baseline (267.825 us; speedup 1.0000x reference)
//
#include <hip/hip_runtime.h>

// Gaussian pyramid, 4 levels. Input (16,3,1024,1024) f32.
// Level0 = copy (fused into level-1 reduce). Level k+1 = replicate-pad-2 +
// separable 5x5, stride 2.
//
// Geometry note: blockDim=(4,64) so a wave covers 4 column-groups x 16 rows.
// Only blocks at bx==0 / bx==gridDim.x-1 contain edge lanes -> the divergent
// clamped path is issued by ~6% of waves instead of 100% (the R3 bug).

typedef float v4f __attribute__((ext_vector_type(4)));  // native vec for nontemporal builtin

__global__ void gpyr_copy_reduce(const float* __restrict__ in,
                                 float* __restrict__ out0,
                                 float* __restrict__ out1,
                                 int Hin, int Win, int Hout, int Wout) {
    const int ox0 = (blockIdx.x * blockDim.x + threadIdx.x) * 4;
    const int oy  = blockIdx.y * blockDim.y + threadIdx.y;
    const int img = blockIdx.z;
    if (ox0 >= Wout || oy >= Hout) return;

    const float k0 = 0.0625f, k1 = 0.25f, k2 = 0.375f;
    const float kk[5] = {k0, k1, k2, k1, k0};

    const float* ip = in + (size_t)img * Hin * Win;

    const int xbase = 2 * ox0 - 4;
    const bool edge = (xbase < 0) || (xbase + 16 > Win);

    float v[11];
#pragma unroll
    for (int i = 0; i < 11; ++i) v[i] = 0.0f;

    float4 cp0a, cp0b, cp1a, cp1b;  // rows 2*oy, 2*oy+1, x [2*ox0, 2*ox0+8)

#pragma unroll
    for (int ky = 0; ky < 5; ++ky) {
        int iy = 2 * oy + ky - 2;
        iy = min(max(iy, 0), Hin - 1);
        const float* rp = ip + (size_t)iy * Win;
        const float w = kk[ky];
        if (!edge) {
            const float4* rp4 = (const float4*)(rp + xbase);
            float4 a = rp4[0], b = rp4[1], c = rp4[2], d = rp4[3];
            if (ky == 2) { cp0a = b; cp0b = c; }
            if (ky == 3) { cp1a = b; cp1b = c; }
            v[0] += w * a.z;  v[1] += w * a.w;
            v[2] += w * b.x;  v[3] += w * b.y;  v[4] += w * b.z;  v[5] += w * b.w;
            v[6] += w * c.x;  v[7] += w * c.y;  v[8] += w * c.z;  v[9] += w * c.w;
            v[10] += w * d.x;
        } else {
#pragma unroll
            for (int i = 0; i < 11; ++i) {
                int ix = 2 * ox0 - 2 + i;
                ix = min(max(ix, 0), Win - 1);
                v[i] += w * rp[ix];
            }
            if (ky == 2) {
                cp0a = *(const float4*)(rp + 2 * ox0);
                cp0b = *(const float4*)(rp + 2 * ox0 + 4);
            }
            if (ky == 3) {
                cp1a = *(const float4*)(rp + 2 * ox0);
                cp1b = *(const float4*)(rp + 2 * ox0 + 4);
            }
        }
    }

    // copy stores (out0 never re-read this launch -> nontemporal)
    {
        float* op = out0 + (size_t)img * Hin * Win + (size_t)(2 * oy) * Win + 2 * ox0;
        __builtin_nontemporal_store(*(v4f*)&cp0a, (v4f*)(op));
        __builtin_nontemporal_store(*(v4f*)&cp0b, (v4f*)(op + 4));
        __builtin_nontemporal_store(*(v4f*)&cp1a, (v4f*)(op + Win));
        __builtin_nontemporal_store(*(v4f*)&cp1b, (v4f*)(op + Win + 4));
    }

    float4 o;
    o.x = k0 * v[0] + k1 * v[1] + k2 * v[2] + k1 * v[3] + k0 * v[4];
    o.y = k0 * v[2] + k1 * v[3] + k2 * v[4] + k1 * v[5] + k0 * v[6];
    o.z = k0 * v[4] + k1 * v[5] + k2 * v[6] + k1 * v[7] + k0 * v[8];
    o.w = k0 * v[6] + k1 * v[7] + k2 * v[8] + k1 * v[9] + k0 * v[10];

    *(float4*)(out1 + (size_t)img * Hout * Wout + (size_t)oy * Wout + ox0) = o;
}

__global__ void gpyr_reduce2(const float* __restrict__ in, float* __restrict__ out,
                             int Hin, int Win, int Hout, int Wout) {
    const int ox0 = (blockIdx.x * blockDim.x + threadIdx.x) * 4;
    const int oy  = blockIdx.y * blockDim.y + threadIdx.y;
    const int img = blockIdx.z;
    if (ox0 >= Wout || oy >= Hout) return;

    const float k0 = 0.0625f, k1 = 0.25f, k2 = 0.375f;
    const float kk[5] = {k0, k1, k2, k1, k0};

    const float* ip = in + (size_t)img * Hin * Win;
    const int xbase = 2 * ox0 - 4;
    const bool edge = (xbase < 0) || (xbase + 16 > Win);

    float v[11];
#pragma unroll
    for (int i = 0; i < 11; ++i) v[i] = 0.0f;

#pragma unroll
    for (int ky = 0; ky < 5; ++ky) {
        int iy = 2 * oy + ky - 2;
        iy = min(max(iy, 0), Hin - 1);
        const float* rp = ip + (size_t)iy * Win;
        const float w = kk[ky];
        if (!edge) {
            const float4* rp4 = (const float4*)(rp + xbase);
            float4 a = rp4[0], b = rp4[1], c = rp4[2], d = rp4[3];
            v[0] += w * a.z;  v[1] += w * a.w;
            v[2] += w * b.x;  v[3] += w * b.y;  v[4] += w * b.z;  v[5] += w * b.w;
            v[6] += w * c.x;  v[7] += w * c.y;  v[8] += w * c.z;  v[9] += w * c.w;
            v[10] += w * d.x;
        } else {
#pragma unroll
            for (int i = 0; i < 11; ++i) {
                int ix = 2 * ox0 - 2 + i;
                ix = min(max(ix, 0), Win - 1);
                v[i] += w * rp[ix];
            }
        }
    }

    float4 o;
    o.x = k0 * v[0] + k1 * v[1] + k2 * v[2] + k1 * v[3] + k0 * v[4];
    o.y = k0 * v[2] + k1 * v[3] + k2 * v[4] + k1 * v[5] + k0 * v[6];
    o.z = k0 * v[4] + k1 * v[5] + k2 * v[6] + k1 * v[7] + k0 * v[8];
    o.w = k0 * v[6] + k1 * v[7] + k2 * v[8] + k1 * v[9] + k0 * v[10];

    *(float4*)(out + (size_t)img * Hout * Wout + (size_t)oy * Wout + ox0) = o;
}

extern "C" void kernel_launch(void* const* d_in, const int* in_sizes, int n_in,
                              void* d_out, int out_size, void* d_ws, size_t ws_size,
                              hipStream_t stream) {
    const float* im = (const float*)d_in[0];
    float* out = (float*)d_out;

    const int NC = 16 * 3;
    const size_t L0 = (size_t)NC * 1024 * 1024;
    const size_t L1 = (size_t)NC * 512 * 512;
    const size_t L2 = (size_t)NC * 256 * 256;

    float* out0 = out;
    float* out1 = out0 + L0;
    float* out2 = out1 + L1;
    float* out3 = out2 + L2;

    // Fused level0 copy + level1 reduce. blockDim=(4,64): edge lanes only in
    // bx==0 / bx==7 blocks.
    {
        int Hout = 512, Wout = 512;
        dim3 block(4, 64, 1);
        dim3 grid((Wout / 4) / 4, Hout / 64, NC);   // (32, 8, 48)
        gpyr_copy_reduce<<<grid, block, 0, stream>>>(im, out0, out1, 1024, 1024, Hout, Wout);
    }

    auto launch_reduce = [&](const float* src, float* dst, int Hin, int Win) {
        int Hout = Hin / 2, Wout = Win / 2;
        dim3 block(4, 64, 1);
        dim3 grid((Wout / 4 + 3) / 4, (Hout + 63) / 64, NC);
        gpyr_reduce2<<<grid, block, 0, stream>>>(src, dst, Hin, Win, Hout, Wout);
    };

    launch_reduce(out1, out2, 512, 512);
    launch_reduce(out2, out3, 256, 256);
}

// Round 6
// 143.608 us; speedup vs baseline: 1.8650x; 1.8650x over previous
//
#include <hip/hip_runtime.h>

// Gaussian pyramid, 4 levels. Input (16,3,1024,1024) f32.
// Level0 copy fused into level-1 reduce. Level k+1 = replicate-pad-2 +
// separable 5x5, stride 2.
//
// Key structure: blockDim=(64,4) -> each wave is one output row (oy uniform),
// lanes cover 256 consecutive output px -> loads are contiguous ~2KB spans.
// Edge handling is BRANCHLESS: every lane does the same 4x float4 loads from
// a clamped base; only the register wiring differs via per-lane selects
// (v_cndmask), so no dual-path load issue (the R2/R3 cost) and no cross-block
// line duplication (the R5 cost).

typedef float v4f __attribute__((ext_vector_type(4)));

__device__ __forceinline__ float S(bool l, bool r, float L, float I, float R) {
    return l ? L : (r ? R : I);
}
__device__ __forceinline__ float4 S4(bool l, bool r, float4 L, float4 I, float4 R) {
    float4 o;
    o.x = S(l, r, L.x, I.x, R.x);
    o.y = S(l, r, L.y, I.y, R.y);
    o.z = S(l, r, L.z, I.z, R.z);
    o.w = S(l, r, L.w, I.w, R.w);
    return o;
}

template <bool FUSE>
__global__ __launch_bounds__(256) void gpyr_reduce(const float* __restrict__ in,
                                                   float* __restrict__ out0,
                                                   float* __restrict__ out1,
                                                   int Hin, int Win, int Hout, int Wout) {
    const int ox0 = (blockIdx.x * blockDim.x + threadIdx.x) * 4;
    const int oy  = blockIdx.y * blockDim.y + threadIdx.y;
    const int img = blockIdx.z;
    if (ox0 >= Wout || oy >= Hout) return;

    const float k0 = 0.0625f, k1 = 0.25f, k2 = 0.375f;
    const float kk[5] = {k0, k1, k2, k1, k0};

    const bool left  = (ox0 == 0);
    const bool right = (2 * ox0 + 12 > Win);
    int xb = 2 * ox0 - 4;
    if (left)  xb = 0;
    if (right) xb = Win - 16;

    const float* ip = in + (size_t)img * Hin * Win;

    float v[11];
#pragma unroll
    for (int i = 0; i < 11; ++i) v[i] = 0.0f;

    float4 cp0A, cp0B, cp1A, cp1B;  // FUSE: rows 2*oy, 2*oy+1, x [2*ox0, 2*ox0+8)

#pragma unroll
    for (int ky = 0; ky < 5; ++ky) {
        int iy = 2 * oy + ky - 2;
        iy = min(max(iy, 0), Hin - 1);
        const float4* rp4 = (const float4*)(ip + (size_t)iy * Win + xb);
        float4 A = rp4[0], B = rp4[1], C = rp4[2], D = rp4[3];

        if (FUSE && ky == 2) { cp0A = S4(left, right, A, B, C); cp0B = S4(left, right, B, C, D); }
        if (FUSE && ky == 3) { cp1A = S4(left, right, A, B, C); cp1B = S4(left, right, B, C, D); }

        const float w = kk[ky];
        // v[i] = input x = 2*ox0 - 2 + i, replicate-clamped.
        // interior: element (2*ox0-2+i) - xb = i+2 of [A,B,C,D]
        // left  (xb=0):      clamp(-2..8)  -> [A.x,A.x,A.x,A.y,A.z,A.w,B.x,B.y,B.z,B.w,C.x]
        // right (xb=Win-16): clamp(..Win-1)-> [B.z,B.w,C.x,C.y,C.z,C.w,D.x,D.y,D.z,D.w,D.w]
        v[0]  += w * S(left, right, A.x, A.z, B.z);
        v[1]  += w * S(left, right, A.x, A.w, B.w);
        v[2]  += w * S(left, right, A.x, B.x, C.x);
        v[3]  += w * S(left, right, A.y, B.y, C.y);
        v[4]  += w * S(left, right, A.z, B.z, C.z);
        v[5]  += w * S(left, right, A.w, B.w, C.w);
        v[6]  += w * S(left, right, B.x, C.x, D.x);
        v[7]  += w * S(left, right, B.y, C.y, D.y);
        v[8]  += w * S(left, right, B.z, C.z, D.z);
        v[9]  += w * S(left, right, B.w, C.w, D.w);
        v[10] += w * S(left, right, C.x, D.x, D.w);
    }

    if (FUSE) {
        float* op = out0 + (size_t)img * Hin * Win + (size_t)(2 * oy) * Win + 2 * ox0;
        __builtin_nontemporal_store(*(v4f*)&cp0A, (v4f*)(op));
        __builtin_nontemporal_store(*(v4f*)&cp0B, (v4f*)(op + 4));
        __builtin_nontemporal_store(*(v4f*)&cp1A, (v4f*)(op + Win));
        __builtin_nontemporal_store(*(v4f*)&cp1B, (v4f*)(op + Win + 4));
    }

    float4 o;
    o.x = k0 * v[0] + k1 * v[1] + k2 * v[2] + k1 * v[3] + k0 * v[4];
    o.y = k0 * v[2] + k1 * v[3] + k2 * v[4] + k1 * v[5] + k0 * v[6];
    o.z = k0 * v[4] + k1 * v[5] + k2 * v[6] + k1 * v[7] + k0 * v[8];
    o.w = k0 * v[6] + k1 * v[7] + k2 * v[8] + k1 * v[9] + k0 * v[10];

    *(float4*)(out1 + (size_t)img * Hout * Wout + (size_t)oy * Wout + ox0) = o;
}

extern "C" void kernel_launch(void* const* d_in, const int* in_sizes, int n_in,
                              void* d_out, int out_size, void* d_ws, size_t ws_size,
                              hipStream_t stream) {
    const float* im = (const float*)d_in[0];
    float* out = (float*)d_out;

    const int NC = 16 * 3;
    const size_t L0 = (size_t)NC * 1024 * 1024;
    const size_t L1 = (size_t)NC * 512 * 512;
    const size_t L2 = (size_t)NC * 256 * 256;

    float* out0 = out;
    float* out1 = out0 + L0;
    float* out2 = out1 + L1;
    float* out3 = out2 + L2;

    auto cfg = [](int Wout, int Hout, dim3& block, dim3& grid) {
        int tpx = Wout / 4; if (tpx > 64) tpx = 64;
        int tpy = 256 / tpx;
        block = dim3(tpx, tpy, 1);
        grid = dim3((Wout / 4 + tpx - 1) / tpx, (Hout + tpy - 1) / tpy, 16 * 3);
    };

    // Fused level0 copy + level1 reduce.
    {
        dim3 block, grid;
        cfg(512, 512, block, grid);
        gpyr_reduce<true><<<grid, block, 0, stream>>>(im, out0, out1, 1024, 1024, 512, 512);
    }
    {
        dim3 block, grid;
        cfg(256, 256, block, grid);
        gpyr_reduce<false><<<grid, block, 0, stream>>>(out1, nullptr, out2, 512, 512, 256, 256);
    }
    {
        dim3 block, grid;
        cfg(128, 128, block, grid);
        gpyr_reduce<false><<<grid, block, 0, stream>>>(out2, nullptr, out3, 256, 256, 128, 128);
    }
}

// Round 7
// 140.603 us; speedup vs baseline: 1.9048x; 1.0214x over previous
//
#include <hip/hip_runtime.h>

// Gaussian pyramid, 4 levels. Input (16,3,1024,1024) f32.
// Level0 copy fused into level-1 reduce. Level k+1 = replicate-pad-2 +
// separable 5x5, stride 2.
//
// blockDim=(64,4): wave = one output row, contiguous ~2KB load spans.
// Edge handling branchless via per-lane selects (v_cndmask).
// out0 copy stores are PLAIN cached stores: the two strided dwordx4 halves
// of each 64-B line merge in L2 before writeback (nontemporal bypassed that
// merge and doubled WRITE_SIZE to 402 MB in R6).

__device__ __forceinline__ float S(bool l, bool r, float L, float I, float R) {
    return l ? L : (r ? R : I);
}
__device__ __forceinline__ float4 S4(bool l, bool r, float4 L, float4 I, float4 R) {
    float4 o;
    o.x = S(l, r, L.x, I.x, R.x);
    o.y = S(l, r, L.y, I.y, R.y);
    o.z = S(l, r, L.z, I.z, R.z);
    o.w = S(l, r, L.w, I.w, R.w);
    return o;
}

template <bool FUSE>
__global__ __launch_bounds__(256) void gpyr_reduce(const float* __restrict__ in,
                                                   float* __restrict__ out0,
                                                   float* __restrict__ out1,
                                                   int Hin, int Win, int Hout, int Wout) {
    const int ox0 = (blockIdx.x * blockDim.x + threadIdx.x) * 4;
    const int oy  = blockIdx.y * blockDim.y + threadIdx.y;
    const int img = blockIdx.z;
    if (ox0 >= Wout || oy >= Hout) return;

    const float k0 = 0.0625f, k1 = 0.25f, k2 = 0.375f;
    const float kk[5] = {k0, k1, k2, k1, k0};

    const bool left  = (ox0 == 0);
    const bool right = (2 * ox0 + 12 > Win);
    int xb = 2 * ox0 - 4;
    if (left)  xb = 0;
    if (right) xb = Win - 16;

    const float* ip = in + (size_t)img * Hin * Win;

    float v[11];
#pragma unroll
    for (int i = 0; i < 11; ++i) v[i] = 0.0f;

    float4 cp0A, cp0B, cp1A, cp1B;  // FUSE: rows 2*oy, 2*oy+1, x [2*ox0, 2*ox0+8)

#pragma unroll
    for (int ky = 0; ky < 5; ++ky) {
        int iy = 2 * oy + ky - 2;
        iy = min(max(iy, 0), Hin - 1);
        const float4* rp4 = (const float4*)(ip + (size_t)iy * Win + xb);
        float4 A = rp4[0], B = rp4[1], C = rp4[2], D = rp4[3];

        if (FUSE && ky == 2) { cp0A = S4(left, right, A, B, C); cp0B = S4(left, right, B, C, D); }
        if (FUSE && ky == 3) { cp1A = S4(left, right, A, B, C); cp1B = S4(left, right, B, C, D); }

        const float w = kk[ky];
        // v[i] = input x = 2*ox0 - 2 + i, replicate-clamped.
        v[0]  += w * S(left, right, A.x, A.z, B.z);
        v[1]  += w * S(left, right, A.x, A.w, B.w);
        v[2]  += w * S(left, right, A.x, B.x, C.x);
        v[3]  += w * S(left, right, A.y, B.y, C.y);
        v[4]  += w * S(left, right, A.z, B.z, C.z);
        v[5]  += w * S(left, right, A.w, B.w, C.w);
        v[6]  += w * S(left, right, B.x, C.x, D.x);
        v[7]  += w * S(left, right, B.y, C.y, D.y);
        v[8]  += w * S(left, right, B.z, C.z, D.z);
        v[9]  += w * S(left, right, B.w, C.w, D.w);
        v[10] += w * S(left, right, C.x, D.x, D.w);
    }

    if (FUSE) {
        float* op = out0 + (size_t)img * Hin * Win + (size_t)(2 * oy) * Win + 2 * ox0;
        *(float4*)(op)           = cp0A;
        *(float4*)(op + 4)       = cp0B;
        *(float4*)(op + Win)     = cp1A;
        *(float4*)(op + Win + 4) = cp1B;
    }

    float4 o;
    o.x = k0 * v[0] + k1 * v[1] + k2 * v[2] + k1 * v[3] + k0 * v[4];
    o.y = k0 * v[2] + k1 * v[3] + k2 * v[4] + k1 * v[5] + k0 * v[6];
    o.z = k0 * v[4] + k1 * v[5] + k2 * v[6] + k1 * v[7] + k0 * v[8];
    o.w = k0 * v[6] + k1 * v[7] + k2 * v[8] + k1 * v[9] + k0 * v[10];

    *(float4*)(out1 + (size_t)img * Hout * Wout + (size_t)oy * Wout + ox0) = o;
}

extern "C" void kernel_launch(void* const* d_in, const int* in_sizes, int n_in,
                              void* d_out, int out_size, void* d_ws, size_t ws_size,
                              hipStream_t stream) {
    const float* im = (const float*)d_in[0];
    float* out = (float*)d_out;

    const int NC = 16 * 3;
    const size_t L0 = (size_t)NC * 1024 * 1024;
    const size_t L1 = (size_t)NC * 512 * 512;
    const size_t L2 = (size_t)NC * 256 * 256;

    float* out0 = out;
    float* out1 = out0 + L0;
    float* out2 = out1 + L1;
    float* out3 = out2 + L2;

    auto cfg = [](int Wout, int Hout, dim3& block, dim3& grid) {
        int tpx = Wout / 4; if (tpx > 64) tpx = 64;
        int tpy = 256 / tpx;
        block = dim3(tpx, tpy, 1);
        grid = dim3((Wout / 4 + tpx - 1) / tpx, (Hout + tpy - 1) / tpy, 16 * 3);
    };

    // Fused level0 copy + level1 reduce.
    {
        dim3 block, grid;
        cfg(512, 512, block, grid);
        gpyr_reduce<true><<<grid, block, 0, stream>>>(im, out0, out1, 1024, 1024, 512, 512);
    }
    {
        dim3 block, grid;
        cfg(256, 256, block, grid);
        gpyr_reduce<false><<<grid, block, 0, stream>>>(out1, nullptr, out2, 512, 512, 256, 256);
    }
    {
        dim3 block, grid;
        cfg(128, 128, block, grid);
        gpyr_reduce<false><<<grid, block, 0, stream>>>(out2, nullptr, out3, 256, 256, 128, 128);
    }
}